// Round 1
// baseline (332.360 us; speedup 1.0000x reference)
//
#include <hip/hip_runtime.h>
#include <stdint.h>

#define NH 16
#define DH 64
#define DM 1024
#define Bz 4
#define Sz 2048

typedef __bf16 bf16x8 __attribute__((ext_vector_type(8)));
typedef float f32x4 __attribute__((ext_vector_type(4)));

// async global(16B/lane) -> LDS (wave-uniform base + lane*16)
#define GLD_LDS16(gsrc, ldst)                                             \
    __builtin_amdgcn_global_load_lds(                                     \
        (const __attribute__((address_space(1))) void*)(gsrc),            \
        (__attribute__((address_space(3))) void*)(ldst), 16, 0, 0)

__device__ __forceinline__ unsigned short f2bf(float f) {
    unsigned u = __float_as_uint(f);
    u += 0x7FFFu + ((u >> 16) & 1u);          // RNE
    return (unsigned short)(u >> 16);
}
__device__ __forceinline__ float bf2f(unsigned short h) {
    return __uint_as_float(((unsigned)h) << 16);
}

// ---------------------------------------------------------------------------
// Dtype detection (f32 vs bf16 storage). flag=1 => f32.
// ---------------------------------------------------------------------------
__global__ void detect_dtype(const unsigned short* __restrict__ xs,
                             int* __restrict__ flagp)
{
    const int t = threadIdx.x;          // 64 threads, 1 block
    int cnt = 0;
    for (int i = 0; i < 64; i++) {
        const unsigned short h = xs[(t * 64 + i) * 2];
        const int e = (h >> 7) & 0xFF;
        if (h != 0 && e >= 100 && e <= 130) cnt++;
    }
#pragma unroll
    for (int off = 32; off >= 1; off >>= 1)
        cnt += __shfl_xor(cnt, off);
    if (t == 0) *flagp = (cnt < 2048) ? 1 : 0;
}

// ---------------------------------------------------------------------------
// Canonicalize 9 tensors into bf16 workspace buffers.
// ---------------------------------------------------------------------------
__global__ __launch_bounds__(256) void convert_inputs(
    const void* s0, const void* s1, const void* s2, const void* s3,
    const void* s4, const void* s5, const void* s6, const void* s7,
    const void* s8,
    unsigned short* d0, unsigned short* d1, unsigned short* d2,
    unsigned short* d3, unsigned short* d4, unsigned short* d5,
    unsigned short* d6, unsigned short* d7, unsigned short* d8,
    const int* __restrict__ flagp)
{
    const void* s; unsigned short* d; int n;
    switch (blockIdx.y) {
        case 0: s = s0; d = d0; n = Bz * Sz * DM; break;   // x
        case 1: s = s1; d = d1; n = DM * DM; break;        // Wq
        case 2: s = s2; d = d2; n = DM * DM; break;        // Wk
        case 3: s = s3; d = d3; n = DM * DM; break;        // Wv
        case 4: s = s4; d = d4; n = DM * DM; break;        // Wo
        case 5: s = s5; d = d5; n = DM; break;             // bq
        case 6: s = s6; d = d6; n = DM; break;             // bk
        case 7: s = s7; d = d7; n = DM; break;             // bv
        default: s = s8; d = d8; n = DM; break;            // bo
    }
    const int flag   = *flagp;
    const int stride = gridDim.x * blockDim.x * 4;
    const int base   = (blockIdx.x * blockDim.x + threadIdx.x) * 4;
    if (flag) {
        const float* sf = (const float*)s;
        for (int i = base; i < n; i += stride) {
            const float4 v = *reinterpret_cast<const float4*>(&sf[i]);
            ushort2 a, b;
            a.x = f2bf(v.x); a.y = f2bf(v.y);
            b.x = f2bf(v.z); b.y = f2bf(v.w);
            *reinterpret_cast<ushort2*>(&d[i])     = a;
            *reinterpret_cast<ushort2*>(&d[i + 2]) = b;
        }
    } else {
        const unsigned short* sh = (const unsigned short*)s;
        for (int i = base; i < n; i += stride)
            *reinterpret_cast<uint2*>(&d[i]) = *reinterpret_cast<const uint2*>(&sh[i]);
    }
}

// ---------------------------------------------------------------------------
// QKV projection: C = X[8192,1024] @ W[1024,1024]^T + b, scattered to
// Q,K: [b*16+h][s][64]  and  Vt: [b*16+h][d][s]   (all bf16)
// grid: (24, 64).
// R7: slab-double-buffered pipeline (T3 minimal 2-phase): stage slab t+1
// while computing slab t; single vmcnt(0)+barrier per 32-wide K step.
// LDS stays 32KB -> 5 blocks/CU.
// ---------------------------------------------------------------------------
__global__ __launch_bounds__(256) void gemm_qkv(
    const unsigned short* __restrict__ X,
    const unsigned short* __restrict__ Wq,
    const unsigned short* __restrict__ Wk,
    const unsigned short* __restrict__ Wv,
    const unsigned short* __restrict__ bq,
    const unsigned short* __restrict__ bk,
    const unsigned short* __restrict__ bv,
    unsigned short* __restrict__ Qb,
    unsigned short* __restrict__ Kb,
    unsigned short* __restrict__ Vtb)
{
    __shared__ __align__(16) unsigned short As[2][128 * 32];
    __shared__ __align__(16) unsigned short Bs[2][128 * 32];
    const int tid  = threadIdx.x;
    const int w    = tid >> 6, lane = tid & 63;
    const int quad = lane >> 4, l15 = lane & 15;
    const int wm   = (w & 1) * 64, wn = (w >> 1) * 64;
    const int bm   = blockIdx.y * 128;
    const int proj = blockIdx.x >> 3;
    const int bn   = (blockIdx.x & 7) * 128;

    const unsigned short* W      = proj == 0 ? Wq : (proj == 1 ? Wk : Wv);
    const unsigned short* bias_p = proj == 0 ? bq : (proj == 1 ? bk : bv);

    const int lrow = lane >> 2;           // 0..15
    const int lcol = (lane & 3) * 8;      // 0,8,16,24

    f32x4 acc[4][4];
    for (int i = 0; i < 4; i++)
        for (int j = 0; j < 4; j++)
            acc[i][j] = f32x4{0.f, 0.f, 0.f, 0.f};

    // stage one 32-wide K slab (A+B) into LDS buffer `buf`
    auto stage = [&](int buf, int ks) {
        const int k0 = ks << 5;
#pragma unroll
        for (int t = 0; t < 2; t++) {
            const int r = w * 32 + t * 16;
            GLD_LDS16(&X[(size_t)(bm + r + lrow) * DM + k0 + lcol], &As[buf][r * 32]);
            GLD_LDS16(&W[(size_t)(bn + r + lrow) * DM + k0 + lcol], &Bs[buf][r * 32]);
        }
    };

    auto compute32 = [&](int cur) {
        bf16x8 af[4], bfr[4];
#pragma unroll
        for (int i = 0; i < 4; i++)
            af[i] = *reinterpret_cast<const bf16x8*>(&As[cur][(wm + i * 16 + l15) * 32 + quad * 8]);
#pragma unroll
        for (int j = 0; j < 4; j++)
            bfr[j] = *reinterpret_cast<const bf16x8*>(&Bs[cur][(wn + j * 16 + l15) * 32 + quad * 8]);
#pragma unroll
        for (int i = 0; i < 4; i++)
#pragma unroll
            for (int j = 0; j < 4; j++)
                acc[i][j] = __builtin_amdgcn_mfma_f32_16x16x32_bf16(af[i], bfr[j], acc[i][j], 0, 0, 0);
    };

    stage(0, 0);
    asm volatile("s_waitcnt vmcnt(0)" ::: "memory");
    __syncthreads();
    for (int t = 0; t < 31; ++t) {
        stage((t + 1) & 1, t + 1);     // in flight during compute
        compute32(t & 1);
        asm volatile("s_waitcnt vmcnt(0)" ::: "memory");
        __syncthreads();
    }
    compute32(1);                      // t = 31

    // epilogue: C layout row = quad*4+r, col = l15
    if (proj < 2) {
        unsigned short* dst = (proj == 0) ? Qb : Kb;
#pragma unroll
        for (int j = 0; j < 4; j++) {
            const int   e    = bn + wn + j * 16 + l15;   // 0..1023
            const int   h    = e >> 6, dd = e & 63;
            const float bias = bf2f(bias_p[e]);
#pragma unroll
            for (int i = 0; i < 4; i++) {
#pragma unroll
                for (int r = 0; r < 4; r++) {
                    const int m = bm + wm + i * 16 + quad * 4 + r;
                    const int b = m >> 11, s = m & 2047;
                    dst[((size_t)(b * NH + h) * Sz + s) * DH + dd] = f2bf(acc[i][j][r] + bias);
                }
            }
        }
    } else {
        // V transposed: 4 consecutive s per lane -> one uint2 (4 bf16) store
#pragma unroll
        for (int j = 0; j < 4; j++) {
            const int   e    = bn + wn + j * 16 + l15;
            const int   h    = e >> 6, dd = e & 63;
            const float bias = bf2f(bias_p[e]);
#pragma unroll
            for (int i = 0; i < 4; i++) {
                const int m0 = bm + wm + i * 16 + quad * 4;     // s-aligned to 4
                const int b  = m0 >> 11, s0 = m0 & 2047;
                const unsigned u0 = __float_as_uint(acc[i][j][0] + bias) + 0x8000u;
                const unsigned u1 = __float_as_uint(acc[i][j][1] + bias) + 0x8000u;
                const unsigned u2 = __float_as_uint(acc[i][j][2] + bias) + 0x8000u;
                const unsigned u3 = __float_as_uint(acc[i][j][3] + bias) + 0x8000u;
                uint2 pk;
                pk.x = __builtin_amdgcn_perm(u1, u0, 0x07060302u);
                pk.y = __builtin_amdgcn_perm(u3, u2, 0x07060302u);
                *reinterpret_cast<uint2*>(
                    &Vtb[((size_t)(b * NH + h) * DH + dd) * Sz + s0]) = pk;
            }
        }
    }
}

// ---------------------------------------------------------------------------
// Flash attention (causal), fixed-max softmax, S^T orientation.
// 8 waves x 16 q = 128 q per block; two passes over chunk pair (c, 15-c).
// grid: (8, 64) = 512 blocks = 2/CU x 8 waves = 16 waves/CU steady.
// R7: T14 async-STAGE split — next K/V tile prefetched into registers
// during current tile's compute; LDS-write after __syncthreads; the barrier
// after the write is RAW s_barrier + lgkmcnt(0) (a __syncthreads there
// would vmcnt(0)-drain the prefetch). kv-tile count per pass is even, so
// the loop is hand-unrolled by 2 with named reg pairs (no runtime-indexed
// register arrays).
// ---------------------------------------------------------------------------
__global__ __launch_bounds__(512) void flash_attn(
    const unsigned short* __restrict__ Qb,    // [64][2048][64]
    const unsigned short* __restrict__ Kb,    // [64][2048][64]
    const unsigned short* __restrict__ Vtb,   // [64][64][2048]
    unsigned short* __restrict__ AOb)         // [4][2048][1024]
{
    __shared__ __align__(16) unsigned short Ks[64 * 72];    // [kv][d]
    __shared__ __align__(16) unsigned short Vs[64 * 72];    // [d][kv]
    __shared__ __align__(16) unsigned short Ps[128 * 72];   // [q][kv], wave-private rows

    const int tid  = threadIdx.x;
    const int w    = tid >> 6, lane = tid & 63;
    const int quad = lane >> 4, l15 = lane & 15;
    const int bh   = blockIdx.y;
    const int cA   = (int)(blockIdx.x & 7);

    const int srow = tid >> 3;            // 0..63  (512 threads)
    const int scc  = (tid & 7) * 8;       // 0..56
    const int hh = bh & 15, bb = bh >> 4;

    for (int pass = 0; pass < 2; pass++) {
        const int chunk = pass ? (15 - cA) : cA;
        const int qb = chunk * 128;
        const int qw = qb + w * 16;                  // wave's 16 q rows

        // Q fragment: B-operand layout (row=q=l15, k=quad*8+j)
        const size_t qbase = ((size_t)bh * Sz + qw + l15) * DH;
        const bf16x8 qf0 = *reinterpret_cast<const bf16x8*>(&Qb[qbase + quad * 8]);
        const bf16x8 qf1 = *reinterpret_cast<const bf16x8*>(&Qb[qbase + 32 + quad * 8]);

        f32x4 o[4];
#pragma unroll
        for (int jd = 0; jd < 4; jd++) o[jd] = f32x4{0.f, 0.f, 0.f, 0.f};
        float lsum = 0.f;

        const int n_kv = qb + 128;                   // multiple of 128

        auto compute = [&](int kb) {
            const bool need_mask = (kb + 64 > qw);
#pragma unroll
            for (int j = 0; j < 4; j++) {
                const bf16x8 kf0 = *reinterpret_cast<const bf16x8*>(&Ks[(j * 16 + l15) * 72 + quad * 8]);
                const bf16x8 kf1 = *reinterpret_cast<const bf16x8*>(&Ks[(j * 16 + l15) * 72 + 32 + quad * 8]);
                f32x4 st = f32x4{0.f, 0.f, 0.f, 0.f};
                st = __builtin_amdgcn_mfma_f32_16x16x32_bf16(kf0, qf0, st, 0, 0, 0);
                st = __builtin_amdgcn_mfma_f32_16x16x32_bf16(kf1, qf1, st, 0, 0, 0);
                // p = exp(S/8) = exp2(S * 0.125*log2(e)); causal mask via select
                const int qa = qw + l15;
                float p[4];
#pragma unroll
                for (int r = 0; r < 4; r++) {
                    float e = __builtin_amdgcn_exp2f(st[r] * 0.18033688011f);
                    if (need_mask) {
                        const int kv = kb + j * 16 + quad * 4 + r;
                        e = (kv <= qa) ? e : 0.f;
                    }
                    p[r] = e;
                }
                lsum += (p[0] + p[1]) + (p[2] + p[3]);
                const unsigned u0 = __float_as_uint(p[0]) + 0x8000u;
                const unsigned u1 = __float_as_uint(p[1]) + 0x8000u;
                const unsigned u2 = __float_as_uint(p[2]) + 0x8000u;
                const unsigned u3 = __float_as_uint(p[3]) + 0x8000u;
                const unsigned pk0 = __builtin_amdgcn_perm(u1, u0, 0x07060302u);
                const unsigned pk1 = __builtin_amdgcn_perm(u3, u2, 0x07060302u);
                const int prow = (w * 16 + l15) * 72 + j * 16 + quad * 4;
                *reinterpret_cast<unsigned*>(&Ps[prow])     = pk0;
                *reinterpret_cast<unsigned*>(&Ps[prow + 2]) = pk1;
            }

            // wave-private Ps rows: in-wave drain only, no barrier
            asm volatile("s_waitcnt lgkmcnt(0)" ::: "memory");

            const bf16x8 pf0 = *reinterpret_cast<const bf16x8*>(&Ps[(w * 16 + l15) * 72 + quad * 8]);
            const bf16x8 pf1 = *reinterpret_cast<const bf16x8*>(&Ps[(w * 16 + l15) * 72 + 32 + quad * 8]);
#pragma unroll
            for (int jd = 0; jd < 4; jd++) {
                const bf16x8 vf0 = *reinterpret_cast<const bf16x8*>(&Vs[(jd * 16 + l15) * 72 + quad * 8]);
                const bf16x8 vf1 = *reinterpret_cast<const bf16x8*>(&Vs[(jd * 16 + l15) * 72 + 32 + quad * 8]);
                o[jd] = __builtin_amdgcn_mfma_f32_16x16x32_bf16(pf0, vf0, o[jd], 0, 0, 0);
                o[jd] = __builtin_amdgcn_mfma_f32_16x16x32_bf16(pf1, vf1, o[jd], 0, 0, 0);
            }
        };

        // prologue: prefetch tile 0 into registers
        uint4 kr0 = *reinterpret_cast<const uint4*>(&Kb[((size_t)bh * Sz + srow) * DH + scc]);
        uint4 vr0 = *reinterpret_cast<const uint4*>(&Vtb[((size_t)bh * DH + srow) * Sz + scc]);
        uint4 kr1, vr1;

        for (int kb = 0; kb < n_kv; kb += 128) {
            // ---------------- tile kb (regs kr0/vr0) ----------------
            __syncthreads();    // prev compute done; drains kr0/vr0 (used now)
            *reinterpret_cast<uint4*>(&Ks[srow * 72 + scc]) = kr0;
            *reinterpret_cast<uint4*>(&Vs[srow * 72 + scc]) = vr0;
            // prefetch tile kb+64 (always exists: n_kv is a multiple of 128)
            kr1 = *reinterpret_cast<const uint4*>(&Kb[((size_t)bh * Sz + kb + 64 + srow) * DH + scc]);
            vr1 = *reinterpret_cast<const uint4*>(&Vtb[((size_t)bh * DH + srow) * Sz + kb + 64 + scc]);
            asm volatile("s_waitcnt lgkmcnt(0)" ::: "memory");
            __builtin_amdgcn_s_barrier();             // raw: keep prefetch in flight
            asm volatile("" ::: "memory");
            if (kb <= qw + 15) compute(kb);

            // ---------------- tile kb+64 (regs kr1/vr1) ----------------
            __syncthreads();
            *reinterpret_cast<uint4*>(&Ks[srow * 72 + scc]) = kr1;
            *reinterpret_cast<uint4*>(&Vs[srow * 72 + scc]) = vr1;
            if (kb + 128 < n_kv) {
                kr0 = *reinterpret_cast<const uint4*>(&Kb[((size_t)bh * Sz + kb + 128 + srow) * DH + scc]);
                vr0 = *reinterpret_cast<const uint4*>(&Vtb[((size_t)bh * DH + srow) * Sz + kb + 128 + scc]);
            }
            asm volatile("s_waitcnt lgkmcnt(0)" ::: "memory");
            __builtin_amdgcn_s_barrier();
            asm volatile("" ::: "memory");
            if (kb + 64 <= qw + 15) compute(kb + 64);
        }

        // reduce lsum across quads (lane holds partial for q = qw + l15)
        lsum += __shfl_xor(lsum, 16);
        lsum += __shfl_xor(lsum, 32);

        // write AO[b][s][h*64+d]; o[jd][r] is q-row quad*4+r, col jd*16+l15
        float linv[4];
#pragma unroll
        for (int r = 0; r < 4; r++)
            linv[r] = 1.0f / __shfl(lsum, quad * 4 + r);
#pragma unroll
        for (int jd = 0; jd < 4; jd++) {
#pragma unroll
            for (int r = 0; r < 4; r++) {
                const int s = qw + quad * 4 + r;
                AOb[((size_t)(bb * Sz + s)) * DM + hh * DH + jd * 16 + l15] =
                    f2bf(o[jd][r] * linv[r]);
            }
        }
    }
}

// ---------------------------------------------------------------------------
// Output projection: out = AO[8192,1024] @ Wo[1024,1024]^T + bo
// Stores f32 or bf16 per the dtype flag.  grid: (8, 64).
// R7: same slab-double-buffered pipeline as gemm_qkv (this kernel has only
// 2 blocks/CU, so intra-block overlap matters most here).
// ---------------------------------------------------------------------------
__global__ __launch_bounds__(256) void gemm_out(
    const unsigned short* __restrict__ A,
    const unsigned short* __restrict__ W,
    const unsigned short* __restrict__ bo,
    void* __restrict__ outv,
    const int* __restrict__ flagp)
{
    __shared__ __align__(16) unsigned short As[2][128 * 32];
    __shared__ __align__(16) unsigned short Bs[2][128 * 32];
    const int tid  = threadIdx.x;
    const int w    = tid >> 6, lane = tid & 63;
    const int quad = lane >> 4, l15 = lane & 15;
    const int wm   = (w & 1) * 64, wn = (w >> 1) * 64;
    const int bm   = blockIdx.y * 128;
    const int bn   = blockIdx.x * 128;

    const int lrow = lane >> 2;
    const int lcol = (lane & 3) * 8;

    f32x4 acc[4][4];
    for (int i = 0; i < 4; i++)
        for (int j = 0; j < 4; j++)
            acc[i][j] = f32x4{0.f, 0.f, 0.f, 0.f};

    auto stage = [&](int buf, int ks) {
        const int k0 = ks << 5;
#pragma unroll
        for (int t = 0; t < 2; t++) {
            const int r = w * 32 + t * 16;
            GLD_LDS16(&A[(size_t)(bm + r + lrow) * DM + k0 + lcol], &As[buf][r * 32]);
            GLD_LDS16(&W[(size_t)(bn + r + lrow) * DM + k0 + lcol], &Bs[buf][r * 32]);
        }
    };

    auto compute32 = [&](int cur) {
        bf16x8 af[4], bfr[4];
#pragma unroll
        for (int i = 0; i < 4; i++)
            af[i] = *reinterpret_cast<const bf16x8*>(&As[cur][(wm + i * 16 + l15) * 32 + quad * 8]);
#pragma unroll
        for (int j = 0; j < 4; j++)
            bfr[j] = *reinterpret_cast<const bf16x8*>(&Bs[cur][(wn + j * 16 + l15) * 32 + quad * 8]);
#pragma unroll
        for (int i = 0; i < 4; i++)
#pragma unroll
            for (int j = 0; j < 4; j++)
                acc[i][j] = __builtin_amdgcn_mfma_f32_16x16x32_bf16(af[i], bfr[j], acc[i][j], 0, 0, 0);
    };

    stage(0, 0);
    asm volatile("s_waitcnt vmcnt(0)" ::: "memory");
    __syncthreads();
    for (int t = 0; t < 31; ++t) {
        stage((t + 1) & 1, t + 1);
        compute32(t & 1);
        asm volatile("s_waitcnt vmcnt(0)" ::: "memory");
        __syncthreads();
    }
    compute32(1);

    const int flag = *flagp;
    float*          outf = (float*)outv;
    unsigned short* outh = (unsigned short*)outv;
#pragma unroll
    for (int j = 0; j < 4; j++) {
        const int   e    = bn + wn + j * 16 + l15;
        const float bias = bf2f(bo[e]);
#pragma unroll
        for (int i = 0; i < 4; i++) {
#pragma unroll
            for (int r = 0; r < 4; r++) {
                const int   m = bm + wm + i * 16 + quad * 4 + r;
                const float v = acc[i][j][r] + bias;
                if (flag) outf[(size_t)m * DM + e] = v;
                else      outh[(size_t)m * DM + e] = f2bf(v);
            }
        }
    }
}

// ---------------------------------------------------------------------------
extern "C" void kernel_launch(void* const* d_in, const int* in_sizes, int n_in,
                              void* d_out, int out_size, void* d_ws, size_t ws_size,
                              hipStream_t stream) {
    // Bind inputs by ELEMENT COUNT (dtype/mask-presence robust)
    const void* x = nullptr;
    const void* Wsrc[4] = {nullptr, nullptr, nullptr, nullptr};
    const void* bsrc[4] = {nullptr, nullptr, nullptr, nullptr};
    int nw = 0, nb = 0;
    for (int i = 0; i < n_in; i++) {
        const int sz = in_sizes[i];
        if (sz == Bz * Sz * DM)            { if (!x) x = d_in[i]; }
        else if (sz == DM * DM)            { if (nw < 4) Wsrc[nw++] = d_in[i]; }
        else if (sz == DM)                 { if (nb < 4) bsrc[nb++] = d_in[i]; }
    }

    char* wsb = (char*)d_ws;
    int*  flagp = (int*)wsb;
    unsigned short* Xc  = (unsigned short*)(wsb + 16);
    const size_t NX = (size_t)Bz * Sz * DM;       // 8,388,608
    const size_t NW = (size_t)DM * DM;            // 1,048,576
    unsigned short* Wc0 = Xc  + NX;
    unsigned short* Wc1 = Wc0 + NW;
    unsigned short* Wc2 = Wc1 + NW;
    unsigned short* Wc3 = Wc2 + NW;
    unsigned short* bc0 = Wc3 + NW;
    unsigned short* bc1 = bc0 + DM;
    unsigned short* bc2 = bc1 + DM;
    unsigned short* bc3 = bc2 + DM;
    unsigned short* Qb  = bc3 + DM;
    const size_t SZ = (size_t)Bz * NH * Sz * DH;  // 8,388,608
    unsigned short* Kb  = Qb  + SZ;
    unsigned short* Vtb = Kb  + SZ;
    unsigned short* AOb = Vtb + SZ;

    detect_dtype<<<1, 64, 0, stream>>>((const unsigned short*)x, flagp);
    convert_inputs<<<dim3(512, 9), 256, 0, stream>>>(
        x, Wsrc[0], Wsrc[1], Wsrc[2], Wsrc[3],
        bsrc[0], bsrc[1], bsrc[2], bsrc[3],
        Xc, Wc0, Wc1, Wc2, Wc3, bc0, bc1, bc2, bc3, flagp);

    gemm_qkv <<<dim3(24, 64), 256, 0, stream>>>(Xc, Wc0, Wc1, Wc2, bc0, bc1, bc2, Qb, Kb, Vtb);
    flash_attn<<<dim3(8, 64), 512, 0, stream>>>(Qb, Kb, Vtb, AOb);
    gemm_out <<<dim3(8, 64), 256, 0, stream>>>(AOb, Wc3, bc3, d_out, flagp);
}

// Round 2
// 314.815 us; speedup vs baseline: 1.0557x; 1.0557x over previous
//
#include <hip/hip_runtime.h>
#include <stdint.h>

#define NH 16
#define DH 64
#define DM 1024
#define Bz 4
#define Sz 2048

typedef __bf16 bf16x8 __attribute__((ext_vector_type(8)));
typedef float f32x4 __attribute__((ext_vector_type(4)));

// async global(16B/lane) -> LDS (wave-uniform base + lane*16)
#define GLD_LDS16(gsrc, ldst)                                             \
    __builtin_amdgcn_global_load_lds(                                     \
        (const __attribute__((address_space(1))) void*)(gsrc),            \
        (__attribute__((address_space(3))) void*)(ldst), 16, 0, 0)

__device__ __forceinline__ unsigned short f2bf(float f) {
    unsigned u = __float_as_uint(f);
    u += 0x7FFFu + ((u >> 16) & 1u);          // RNE
    return (unsigned short)(u >> 16);
}
__device__ __forceinline__ float bf2f(unsigned short h) {
    return __uint_as_float(((unsigned)h) << 16);
}

// ---------------------------------------------------------------------------
// Dtype detection (f32 vs bf16 storage). flag=1 => f32.
// ---------------------------------------------------------------------------
__global__ void detect_dtype(const unsigned short* __restrict__ xs,
                             int* __restrict__ flagp)
{
    const int t = threadIdx.x;          // 64 threads, 1 block
    int cnt = 0;
    for (int i = 0; i < 64; i++) {
        const unsigned short h = xs[(t * 64 + i) * 2];
        const int e = (h >> 7) & 0xFF;
        if (h != 0 && e >= 100 && e <= 130) cnt++;
    }
#pragma unroll
    for (int off = 32; off >= 1; off >>= 1)
        cnt += __shfl_xor(cnt, off);
    if (t == 0) *flagp = (cnt < 2048) ? 1 : 0;
}

// ---------------------------------------------------------------------------
// Canonicalize 9 tensors into bf16 workspace buffers.
// ---------------------------------------------------------------------------
__global__ __launch_bounds__(256) void convert_inputs(
    const void* s0, const void* s1, const void* s2, const void* s3,
    const void* s4, const void* s5, const void* s6, const void* s7,
    const void* s8,
    unsigned short* d0, unsigned short* d1, unsigned short* d2,
    unsigned short* d3, unsigned short* d4, unsigned short* d5,
    unsigned short* d6, unsigned short* d7, unsigned short* d8,
    const int* __restrict__ flagp)
{
    const void* s; unsigned short* d; int n;
    switch (blockIdx.y) {
        case 0: s = s0; d = d0; n = Bz * Sz * DM; break;   // x
        case 1: s = s1; d = d1; n = DM * DM; break;        // Wq
        case 2: s = s2; d = d2; n = DM * DM; break;        // Wk
        case 3: s = s3; d = d3; n = DM * DM; break;        // Wv
        case 4: s = s4; d = d4; n = DM * DM; break;        // Wo
        case 5: s = s5; d = d5; n = DM; break;             // bq
        case 6: s = s6; d = d6; n = DM; break;             // bk
        case 7: s = s7; d = d7; n = DM; break;             // bv
        default: s = s8; d = d8; n = DM; break;            // bo
    }
    const int flag   = *flagp;
    const int stride = gridDim.x * blockDim.x * 4;
    const int base   = (blockIdx.x * blockDim.x + threadIdx.x) * 4;
    if (flag) {
        const float* sf = (const float*)s;
        for (int i = base; i < n; i += stride) {
            const float4 v = *reinterpret_cast<const float4*>(&sf[i]);
            ushort2 a, b;
            a.x = f2bf(v.x); a.y = f2bf(v.y);
            b.x = f2bf(v.z); b.y = f2bf(v.w);
            *reinterpret_cast<ushort2*>(&d[i])     = a;
            *reinterpret_cast<ushort2*>(&d[i + 2]) = b;
        }
    } else {
        const unsigned short* sh = (const unsigned short*)s;
        for (int i = base; i < n; i += stride)
            *reinterpret_cast<uint2*>(&d[i]) = *reinterpret_cast<const uint2*>(&sh[i]);
    }
}

// ---------------------------------------------------------------------------
// QKV projection: C = X[8192,1024] @ W[1024,1024]^T + b, scattered to
// Q,K: [b*16+h][s][64]  and  Vt: [b*16+h][d][s]   (all bf16)
// grid: (24, 64).
// R8: depth-4 slab pipeline (T3+T4). 4 LDS buffers of one 32-wide K slab
// each; stage(t+2) issued 2 iterations ahead; counted s_waitcnt vmcnt(8)
// (= 2 stages x 4 loads in flight) BEFORE a raw s_barrier; compute(t) after.
// Hazard table (region barrier(t)..barrier(t+1)): compute(t) reads buf t%4,
// stage(t+3) writes (t+3)%4 -> disjoint. nbuf=3 would race. Tail peeled to
// vmcnt(4)/vmcnt(0) (vmcnt(8) would pass while the last stages are still in
// flight). __syncthreads is NOT used in the main loop: it drains vmcnt(0).
// LDS 64KB -> 2 blocks/CU (trade occupancy for a correct deep pipeline).
// ---------------------------------------------------------------------------
__global__ __launch_bounds__(256) void gemm_qkv(
    const unsigned short* __restrict__ X,
    const unsigned short* __restrict__ Wq,
    const unsigned short* __restrict__ Wk,
    const unsigned short* __restrict__ Wv,
    const unsigned short* __restrict__ bq,
    const unsigned short* __restrict__ bk,
    const unsigned short* __restrict__ bv,
    unsigned short* __restrict__ Qb,
    unsigned short* __restrict__ Kb,
    unsigned short* __restrict__ Vtb)
{
    __shared__ __align__(16) unsigned short As[4][128 * 32];
    __shared__ __align__(16) unsigned short Bs[4][128 * 32];
    const int tid  = threadIdx.x;
    const int w    = tid >> 6, lane = tid & 63;
    const int quad = lane >> 4, l15 = lane & 15;
    const int wm   = (w & 1) * 64, wn = (w >> 1) * 64;
    const int bm   = blockIdx.y * 128;
    const int proj = blockIdx.x >> 3;
    const int bn   = (blockIdx.x & 7) * 128;

    const unsigned short* W      = proj == 0 ? Wq : (proj == 1 ? Wk : Wv);
    const unsigned short* bias_p = proj == 0 ? bq : (proj == 1 ? bk : bv);

    const int lrow = lane >> 2;           // 0..15
    const int lcol = (lane & 3) * 8;      // 0,8,16,24

    f32x4 acc[4][4];
    for (int i = 0; i < 4; i++)
        for (int j = 0; j < 4; j++)
            acc[i][j] = f32x4{0.f, 0.f, 0.f, 0.f};

    // stage one 32-wide K slab (A+B) into LDS buffer `buf` (4 loads/wave)
    auto stage = [&](int buf, int ks) {
        const int k0 = ks << 5;
#pragma unroll
        for (int t = 0; t < 2; t++) {
            const int r = w * 32 + t * 16;
            GLD_LDS16(&X[(size_t)(bm + r + lrow) * DM + k0 + lcol], &As[buf][r * 32]);
            GLD_LDS16(&W[(size_t)(bn + r + lrow) * DM + k0 + lcol], &Bs[buf][r * 32]);
        }
    };

    auto compute32 = [&](int cur) {
        bf16x8 af[4], bfr[4];
#pragma unroll
        for (int i = 0; i < 4; i++)
            af[i] = *reinterpret_cast<const bf16x8*>(&As[cur][(wm + i * 16 + l15) * 32 + quad * 8]);
#pragma unroll
        for (int j = 0; j < 4; j++)
            bfr[j] = *reinterpret_cast<const bf16x8*>(&Bs[cur][(wn + j * 16 + l15) * 32 + quad * 8]);
#pragma unroll
        for (int i = 0; i < 4; i++)
#pragma unroll
            for (int j = 0; j < 4; j++)
                acc[i][j] = __builtin_amdgcn_mfma_f32_16x16x32_bf16(af[i], bfr[j], acc[i][j], 0, 0, 0);
    };

    // prologue: 2 slabs in flight
    stage(0, 0);
    stage(1, 1);
    // main loop: stage 2 ahead, wait on the stage from 2 iterations ago
    for (int t = 0; t < 30; ++t) {
        stage((t + 2) & 3, t + 2);
        asm volatile("s_waitcnt vmcnt(8)" ::: "memory");   // stage(t) landed
        __builtin_amdgcn_s_barrier();                      // all waves' stage(t) landed
        compute32(t & 3);
    }
    // tail: t = 30 (only stage(31) may be outstanding)
    asm volatile("s_waitcnt vmcnt(4)" ::: "memory");
    __builtin_amdgcn_s_barrier();
    compute32(30 & 3);
    // tail: t = 31
    asm volatile("s_waitcnt vmcnt(0)" ::: "memory");
    __builtin_amdgcn_s_barrier();
    compute32(31 & 3);

    // epilogue: C layout row = quad*4+r, col = l15
    if (proj < 2) {
        unsigned short* dst = (proj == 0) ? Qb : Kb;
#pragma unroll
        for (int j = 0; j < 4; j++) {
            const int   e    = bn + wn + j * 16 + l15;   // 0..1023
            const int   h    = e >> 6, dd = e & 63;
            const float bias = bf2f(bias_p[e]);
#pragma unroll
            for (int i = 0; i < 4; i++) {
#pragma unroll
                for (int r = 0; r < 4; r++) {
                    const int m = bm + wm + i * 16 + quad * 4 + r;
                    const int b = m >> 11, s = m & 2047;
                    dst[((size_t)(b * NH + h) * Sz + s) * DH + dd] = f2bf(acc[i][j][r] + bias);
                }
            }
        }
    } else {
        // V transposed: 4 consecutive s per lane -> one uint2 (4 bf16) store
#pragma unroll
        for (int j = 0; j < 4; j++) {
            const int   e    = bn + wn + j * 16 + l15;
            const int   h    = e >> 6, dd = e & 63;
            const float bias = bf2f(bias_p[e]);
#pragma unroll
            for (int i = 0; i < 4; i++) {
                const int m0 = bm + wm + i * 16 + quad * 4;     // s-aligned to 4
                const int b  = m0 >> 11, s0 = m0 & 2047;
                const unsigned u0 = __float_as_uint(acc[i][j][0] + bias) + 0x8000u;
                const unsigned u1 = __float_as_uint(acc[i][j][1] + bias) + 0x8000u;
                const unsigned u2 = __float_as_uint(acc[i][j][2] + bias) + 0x8000u;
                const unsigned u3 = __float_as_uint(acc[i][j][3] + bias) + 0x8000u;
                uint2 pk;
                pk.x = __builtin_amdgcn_perm(u1, u0, 0x07060302u);
                pk.y = __builtin_amdgcn_perm(u3, u2, 0x07060302u);
                *reinterpret_cast<uint2*>(
                    &Vtb[((size_t)(b * NH + h) * DH + dd) * Sz + s0]) = pk;
            }
        }
    }
}

// ---------------------------------------------------------------------------
// Flash attention (causal), fixed-max softmax, S^T orientation.
// 8 waves x 16 q = 128 q per block; two passes over chunk pair (c, 15-c).
// grid: (8, 64) = 512 blocks = 2/CU x 8 waves = 16 waves/CU steady.
// T14 async-STAGE split — next K/V tile prefetched into registers during
// current tile's compute; LDS-write after __syncthreads; the barrier after
// the write is RAW s_barrier + lgkmcnt(0) (a __syncthreads there would
// vmcnt(0)-drain the prefetch). kv-tile count per pass is even, so the loop
// is hand-unrolled by 2 with named reg pairs (rule #20: no runtime-indexed
// register arrays).
// ---------------------------------------------------------------------------
__global__ __launch_bounds__(512) void flash_attn(
    const unsigned short* __restrict__ Qb,    // [64][2048][64]
    const unsigned short* __restrict__ Kb,    // [64][2048][64]
    const unsigned short* __restrict__ Vtb,   // [64][64][2048]
    unsigned short* __restrict__ AOb)         // [4][2048][1024]
{
    __shared__ __align__(16) unsigned short Ks[64 * 72];    // [kv][d]
    __shared__ __align__(16) unsigned short Vs[64 * 72];    // [d][kv]
    __shared__ __align__(16) unsigned short Ps[128 * 72];   // [q][kv], wave-private rows

    const int tid  = threadIdx.x;
    const int w    = tid >> 6, lane = tid & 63;
    const int quad = lane >> 4, l15 = lane & 15;
    const int bh   = blockIdx.y;
    const int cA   = (int)(blockIdx.x & 7);

    const int srow = tid >> 3;            // 0..63  (512 threads)
    const int scc  = (tid & 7) * 8;       // 0..56
    const int hh = bh & 15, bb = bh >> 4;

    for (int pass = 0; pass < 2; pass++) {
        const int chunk = pass ? (15 - cA) : cA;
        const int qb = chunk * 128;
        const int qw = qb + w * 16;                  // wave's 16 q rows

        // Q fragment: B-operand layout (row=q=l15, k=quad*8+j)
        const size_t qbase = ((size_t)bh * Sz + qw + l15) * DH;
        const bf16x8 qf0 = *reinterpret_cast<const bf16x8*>(&Qb[qbase + quad * 8]);
        const bf16x8 qf1 = *reinterpret_cast<const bf16x8*>(&Qb[qbase + 32 + quad * 8]);

        f32x4 o[4];
#pragma unroll
        for (int jd = 0; jd < 4; jd++) o[jd] = f32x4{0.f, 0.f, 0.f, 0.f};
        float lsum = 0.f;

        const int n_kv = qb + 128;                   // multiple of 128

        auto compute = [&](int kb) {
            const bool need_mask = (kb + 64 > qw);
#pragma unroll
            for (int j = 0; j < 4; j++) {
                const bf16x8 kf0 = *reinterpret_cast<const bf16x8*>(&Ks[(j * 16 + l15) * 72 + quad * 8]);
                const bf16x8 kf1 = *reinterpret_cast<const bf16x8*>(&Ks[(j * 16 + l15) * 72 + 32 + quad * 8]);
                f32x4 st = f32x4{0.f, 0.f, 0.f, 0.f};
                st = __builtin_amdgcn_mfma_f32_16x16x32_bf16(kf0, qf0, st, 0, 0, 0);
                st = __builtin_amdgcn_mfma_f32_16x16x32_bf16(kf1, qf1, st, 0, 0, 0);
                // p = exp(S/8) = exp2(S * 0.125*log2(e)); causal mask via select
                const int qa = qw + l15;
                float p[4];
#pragma unroll
                for (int r = 0; r < 4; r++) {
                    float e = __builtin_amdgcn_exp2f(st[r] * 0.18033688011f);
                    if (need_mask) {
                        const int kv = kb + j * 16 + quad * 4 + r;
                        e = (kv <= qa) ? e : 0.f;
                    }
                    p[r] = e;
                }
                lsum += (p[0] + p[1]) + (p[2] + p[3]);
                const unsigned u0 = __float_as_uint(p[0]) + 0x8000u;
                const unsigned u1 = __float_as_uint(p[1]) + 0x8000u;
                const unsigned u2 = __float_as_uint(p[2]) + 0x8000u;
                const unsigned u3 = __float_as_uint(p[3]) + 0x8000u;
                const unsigned pk0 = __builtin_amdgcn_perm(u1, u0, 0x07060302u);
                const unsigned pk1 = __builtin_amdgcn_perm(u3, u2, 0x07060302u);
                const int prow = (w * 16 + l15) * 72 + j * 16 + quad * 4;
                *reinterpret_cast<unsigned*>(&Ps[prow])     = pk0;
                *reinterpret_cast<unsigned*>(&Ps[prow + 2]) = pk1;
            }

            // wave-private Ps rows: in-wave drain only, no barrier
            asm volatile("s_waitcnt lgkmcnt(0)" ::: "memory");

            const bf16x8 pf0 = *reinterpret_cast<const bf16x8*>(&Ps[(w * 16 + l15) * 72 + quad * 8]);
            const bf16x8 pf1 = *reinterpret_cast<const bf16x8*>(&Ps[(w * 16 + l15) * 72 + 32 + quad * 8]);
#pragma unroll
            for (int jd = 0; jd < 4; jd++) {
                const bf16x8 vf0 = *reinterpret_cast<const bf16x8*>(&Vs[(jd * 16 + l15) * 72 + quad * 8]);
                const bf16x8 vf1 = *reinterpret_cast<const bf16x8*>(&Vs[(jd * 16 + l15) * 72 + 32 + quad * 8]);
                o[jd] = __builtin_amdgcn_mfma_f32_16x16x32_bf16(pf0, vf0, o[jd], 0, 0, 0);
                o[jd] = __builtin_amdgcn_mfma_f32_16x16x32_bf16(pf1, vf1, o[jd], 0, 0, 0);
            }
        };

        // prologue: prefetch tile 0 into registers
        uint4 kr0 = *reinterpret_cast<const uint4*>(&Kb[((size_t)bh * Sz + srow) * DH + scc]);
        uint4 vr0 = *reinterpret_cast<const uint4*>(&Vtb[((size_t)bh * DH + srow) * Sz + scc]);
        uint4 kr1, vr1;

        for (int kb = 0; kb < n_kv; kb += 128) {
            // ---------------- tile kb (regs kr0/vr0) ----------------
            __syncthreads();    // prev compute done; drains kr0/vr0 (used now)
            *reinterpret_cast<uint4*>(&Ks[srow * 72 + scc]) = kr0;
            *reinterpret_cast<uint4*>(&Vs[srow * 72 + scc]) = vr0;
            // prefetch tile kb+64 (always exists: n_kv is a multiple of 128)
            kr1 = *reinterpret_cast<const uint4*>(&Kb[((size_t)bh * Sz + kb + 64 + srow) * DH + scc]);
            vr1 = *reinterpret_cast<const uint4*>(&Vtb[((size_t)bh * DH + srow) * Sz + kb + 64 + scc]);
            asm volatile("s_waitcnt lgkmcnt(0)" ::: "memory");
            __builtin_amdgcn_s_barrier();             // raw: keep prefetch in flight
            asm volatile("" ::: "memory");
            if (kb <= qw + 15) compute(kb);

            // ---------------- tile kb+64 (regs kr1/vr1) ----------------
            __syncthreads();
            *reinterpret_cast<uint4*>(&Ks[srow * 72 + scc]) = kr1;
            *reinterpret_cast<uint4*>(&Vs[srow * 72 + scc]) = vr1;
            if (kb + 128 < n_kv) {
                kr0 = *reinterpret_cast<const uint4*>(&Kb[((size_t)bh * Sz + kb + 128 + srow) * DH + scc]);
                vr0 = *reinterpret_cast<const uint4*>(&Vtb[((size_t)bh * DH + srow) * Sz + kb + 128 + scc]);
            }
            asm volatile("s_waitcnt lgkmcnt(0)" ::: "memory");
            __builtin_amdgcn_s_barrier();
            asm volatile("" ::: "memory");
            if (kb + 64 <= qw + 15) compute(kb + 64);
        }

        // reduce lsum across quads (lane holds partial for q = qw + l15)
        lsum += __shfl_xor(lsum, 16);
        lsum += __shfl_xor(lsum, 32);

        // write AO[b][s][h*64+d]; o[jd][r] is q-row quad*4+r, col jd*16+l15
        float linv[4];
#pragma unroll
        for (int r = 0; r < 4; r++)
            linv[r] = 1.0f / __shfl(lsum, quad * 4 + r);
#pragma unroll
        for (int jd = 0; jd < 4; jd++) {
#pragma unroll
            for (int r = 0; r < 4; r++) {
                const int s = qw + quad * 4 + r;
                AOb[((size_t)(bb * Sz + s)) * DM + hh * DH + jd * 16 + l15] =
                    f2bf(o[jd][r] * linv[r]);
            }
        }
    }
}

// ---------------------------------------------------------------------------
// Output projection: out = AO[8192,1024] @ Wo[1024,1024]^T + bo
// Stores f32 or bf16 per the dtype flag.  grid: (8, 64).
// R8: same depth-4 slab pipeline as gemm_qkv. This kernel was already at
// 2 blocks/CU, so the 64KB LDS costs nothing here.
// ---------------------------------------------------------------------------
__global__ __launch_bounds__(256) void gemm_out(
    const unsigned short* __restrict__ A,
    const unsigned short* __restrict__ W,
    const unsigned short* __restrict__ bo,
    void* __restrict__ outv,
    const int* __restrict__ flagp)
{
    __shared__ __align__(16) unsigned short As[4][128 * 32];
    __shared__ __align__(16) unsigned short Bs[4][128 * 32];
    const int tid  = threadIdx.x;
    const int w    = tid >> 6, lane = tid & 63;
    const int quad = lane >> 4, l15 = lane & 15;
    const int wm   = (w & 1) * 64, wn = (w >> 1) * 64;
    const int bm   = blockIdx.y * 128;
    const int bn   = blockIdx.x * 128;

    const int lrow = lane >> 2;
    const int lcol = (lane & 3) * 8;

    f32x4 acc[4][4];
    for (int i = 0; i < 4; i++)
        for (int j = 0; j < 4; j++)
            acc[i][j] = f32x4{0.f, 0.f, 0.f, 0.f};

    auto stage = [&](int buf, int ks) {
        const int k0 = ks << 5;
#pragma unroll
        for (int t = 0; t < 2; t++) {
            const int r = w * 32 + t * 16;
            GLD_LDS16(&A[(size_t)(bm + r + lrow) * DM + k0 + lcol], &As[buf][r * 32]);
            GLD_LDS16(&W[(size_t)(bn + r + lrow) * DM + k0 + lcol], &Bs[buf][r * 32]);
        }
    };

    auto compute32 = [&](int cur) {
        bf16x8 af[4], bfr[4];
#pragma unroll
        for (int i = 0; i < 4; i++)
            af[i] = *reinterpret_cast<const bf16x8*>(&As[cur][(wm + i * 16 + l15) * 32 + quad * 8]);
#pragma unroll
        for (int j = 0; j < 4; j++)
            bfr[j] = *reinterpret_cast<const bf16x8*>(&Bs[cur][(wn + j * 16 + l15) * 32 + quad * 8]);
#pragma unroll
        for (int i = 0; i < 4; i++)
#pragma unroll
            for (int j = 0; j < 4; j++)
                acc[i][j] = __builtin_amdgcn_mfma_f32_16x16x32_bf16(af[i], bfr[j], acc[i][j], 0, 0, 0);
    };

    stage(0, 0);
    stage(1, 1);
    for (int t = 0; t < 30; ++t) {
        stage((t + 2) & 3, t + 2);
        asm volatile("s_waitcnt vmcnt(8)" ::: "memory");
        __builtin_amdgcn_s_barrier();
        compute32(t & 3);
    }
    asm volatile("s_waitcnt vmcnt(4)" ::: "memory");
    __builtin_amdgcn_s_barrier();
    compute32(30 & 3);
    asm volatile("s_waitcnt vmcnt(0)" ::: "memory");
    __builtin_amdgcn_s_barrier();
    compute32(31 & 3);

    const int flag = *flagp;
    float*          outf = (float*)outv;
    unsigned short* outh = (unsigned short*)outv;
#pragma unroll
    for (int j = 0; j < 4; j++) {
        const int   e    = bn + wn + j * 16 + l15;
        const float bias = bf2f(bo[e]);
#pragma unroll
        for (int i = 0; i < 4; i++) {
#pragma unroll
            for (int r = 0; r < 4; r++) {
                const int   m = bm + wm + i * 16 + quad * 4 + r;
                const float v = acc[i][j][r] + bias;
                if (flag) outf[(size_t)m * DM + e] = v;
                else      outh[(size_t)m * DM + e] = f2bf(v);
            }
        }
    }
}

// ---------------------------------------------------------------------------
extern "C" void kernel_launch(void* const* d_in, const int* in_sizes, int n_in,
                              void* d_out, int out_size, void* d_ws, size_t ws_size,
                              hipStream_t stream) {
    // Bind inputs by ELEMENT COUNT (dtype/mask-presence robust)
    const void* x = nullptr;
    const void* Wsrc[4] = {nullptr, nullptr, nullptr, nullptr};
    const void* bsrc[4] = {nullptr, nullptr, nullptr, nullptr};
    int nw = 0, nb = 0;
    for (int i = 0; i < n_in; i++) {
        const int sz = in_sizes[i];
        if (sz == Bz * Sz * DM)            { if (!x) x = d_in[i]; }
        else if (sz == DM * DM)            { if (nw < 4) Wsrc[nw++] = d_in[i]; }
        else if (sz == DM)                 { if (nb < 4) bsrc[nb++] = d_in[i]; }
    }

    char* wsb = (char*)d_ws;
    int*  flagp = (int*)wsb;
    unsigned short* Xc  = (unsigned short*)(wsb + 16);
    const size_t NX = (size_t)Bz * Sz * DM;       // 8,388,608
    const size_t NW = (size_t)DM * DM;            // 1,048,576
    unsigned short* Wc0 = Xc  + NX;
    unsigned short* Wc1 = Wc0 + NW;
    unsigned short* Wc2 = Wc1 + NW;
    unsigned short* Wc3 = Wc2 + NW;
    unsigned short* bc0 = Wc3 + NW;
    unsigned short* bc1 = bc0 + DM;
    unsigned short* bc2 = bc1 + DM;
    unsigned short* bc3 = bc2 + DM;
    unsigned short* Qb  = bc3 + DM;
    const size_t SZ = (size_t)Bz * NH * Sz * DH;  // 8,388,608
    unsigned short* Kb  = Qb  + SZ;
    unsigned short* Vtb = Kb  + SZ;
    unsigned short* AOb = Vtb + SZ;

    detect_dtype<<<1, 64, 0, stream>>>((const unsigned short*)x, flagp);
    convert_inputs<<<dim3(512, 9), 256, 0, stream>>>(
        x, Wsrc[0], Wsrc[1], Wsrc[2], Wsrc[3],
        bsrc[0], bsrc[1], bsrc[2], bsrc[3],
        Xc, Wc0, Wc1, Wc2, Wc3, bc0, bc1, bc2, bc3, flagp);

    gemm_qkv <<<dim3(24, 64), 256, 0, stream>>>(Xc, Wc0, Wc1, Wc2, bc0, bc1, bc2, Qb, Kb, Vtb);
    flash_attn<<<dim3(8, 64), 512, 0, stream>>>(Qb, Kb, Vtb, AOb);
    gemm_out <<<dim3(8, 64), 256, 0, stream>>>(AOb, Wc3, bc3, d_out, flagp);
}

// Round 5
// 303.565 us; speedup vs baseline: 1.0949x; 1.0371x over previous
//
#include <hip/hip_runtime.h>
#include <stdint.h>

#define NH 16
#define DH 64
#define DM 1024
#define Bz 4
#define Sz 2048

typedef __bf16 bf16x8 __attribute__((ext_vector_type(8)));
typedef float f32x4 __attribute__((ext_vector_type(4)));

// async global(16B/lane) -> LDS (wave-uniform base + lane*16)
#define GLD_LDS16(gsrc, ldst)                                             \
    __builtin_amdgcn_global_load_lds(                                     \
        (const __attribute__((address_space(1))) void*)(gsrc),            \
        (__attribute__((address_space(3))) void*)(ldst), 16, 0, 0)

__device__ __forceinline__ unsigned short f2bf(float f) {
    unsigned u = __float_as_uint(f);
    u += 0x7FFFu + ((u >> 16) & 1u);          // RNE
    return (unsigned short)(u >> 16);
}
__device__ __forceinline__ float bf2f(unsigned short h) {
    return __uint_as_float(((unsigned)h) << 16);
}

// ---------------------------------------------------------------------------
// Dtype detection (f32 vs bf16 storage). flag=1 => f32.
// ---------------------------------------------------------------------------
__global__ void detect_dtype(const unsigned short* __restrict__ xs,
                             int* __restrict__ flagp)
{
    const int t = threadIdx.x;          // 64 threads, 1 block
    int cnt = 0;
    for (int i = 0; i < 64; i++) {
        const unsigned short h = xs[(t * 64 + i) * 2];
        const int e = (h >> 7) & 0xFF;
        if (h != 0 && e >= 100 && e <= 130) cnt++;
    }
#pragma unroll
    for (int off = 32; off >= 1; off >>= 1)
        cnt += __shfl_xor(cnt, off);
    if (t == 0) *flagp = (cnt < 2048) ? 1 : 0;
}

// ---------------------------------------------------------------------------
// Canonicalize 9 tensors into bf16 workspace buffers.
// ---------------------------------------------------------------------------
__global__ __launch_bounds__(256) void convert_inputs(
    const void* s0, const void* s1, const void* s2, const void* s3,
    const void* s4, const void* s5, const void* s6, const void* s7,
    const void* s8,
    unsigned short* d0, unsigned short* d1, unsigned short* d2,
    unsigned short* d3, unsigned short* d4, unsigned short* d5,
    unsigned short* d6, unsigned short* d7, unsigned short* d8,
    const int* __restrict__ flagp)
{
    const void* s; unsigned short* d; int n;
    switch (blockIdx.y) {
        case 0: s = s0; d = d0; n = Bz * Sz * DM; break;   // x
        case 1: s = s1; d = d1; n = DM * DM; break;        // Wq
        case 2: s = s2; d = d2; n = DM * DM; break;        // Wk
        case 3: s = s3; d = d3; n = DM * DM; break;        // Wv
        case 4: s = s4; d = d4; n = DM * DM; break;        // Wo
        case 5: s = s5; d = d5; n = DM; break;             // bq
        case 6: s = s6; d = d6; n = DM; break;             // bk
        case 7: s = s7; d = d7; n = DM; break;             // bv
        default: s = s8; d = d8; n = DM; break;            // bo
    }
    const int flag   = *flagp;
    const int stride = gridDim.x * blockDim.x * 4;
    const int base   = (blockIdx.x * blockDim.x + threadIdx.x) * 4;
    if (flag) {
        const float* sf = (const float*)s;
        for (int i = base; i < n; i += stride) {
            const float4 v = *reinterpret_cast<const float4*>(&sf[i]);
            ushort2 a, b;
            a.x = f2bf(v.x); a.y = f2bf(v.y);
            b.x = f2bf(v.z); b.y = f2bf(v.w);
            *reinterpret_cast<ushort2*>(&d[i])     = a;
            *reinterpret_cast<ushort2*>(&d[i + 2]) = b;
        }
    } else {
        const unsigned short* sh = (const unsigned short*)s;
        for (int i = base; i < n; i += stride)
            *reinterpret_cast<uint2*>(&d[i]) = *reinterpret_cast<const uint2*>(&sh[i]);
    }
}

// ---------------------------------------------------------------------------
// QKV projection: C = X[8192,1024] @ W[1024,1024]^T + b, scattered to
// Q,K: [b*16+h][s][64]  and  Vt: [b*16+h][d][s]   (all bf16)
// grid: (24, 64) = 1536 blocks.
// R9: XCD-locality remap (T1). flat%8 = XCD (round-robin dispatch). XCD k
// owns bm-rows [8k,8k+8) for all (proj,bn), ordered proj-outer so the ~64
// concurrently-resident blocks per XCD share X-chunk(2MB)+W-proj(2MB) = 4MB
// = exactly one XCD L2. Previously the 24 blocks sharing an X panel were
// spread over all 8 XCDs -> panel replicated into 8 L2s, staging reads
// missing to L3/HBM latency (Little's-law bound; R0==R2 invariance).
// Keeps R8's depth-2/nbuf-4 counted-vmcnt pipeline (hazard-verified).
// ---------------------------------------------------------------------------
__global__ __launch_bounds__(256) void gemm_qkv(
    const unsigned short* __restrict__ X,
    const unsigned short* __restrict__ Wq,
    const unsigned short* __restrict__ Wk,
    const unsigned short* __restrict__ Wv,
    const unsigned short* __restrict__ bq,
    const unsigned short* __restrict__ bk,
    const unsigned short* __restrict__ bv,
    unsigned short* __restrict__ Qb,
    unsigned short* __restrict__ Kb,
    unsigned short* __restrict__ Vtb)
{
    __shared__ __align__(16) unsigned short As[4][128 * 32];
    __shared__ __align__(16) unsigned short Bs[4][128 * 32];
    const int tid  = threadIdx.x;
    const int w    = tid >> 6, lane = tid & 63;
    const int quad = lane >> 4, l15 = lane & 15;
    const int wm   = (w & 1) * 64, wn = (w >> 1) * 64;

    // XCD-locality remap: flat -> (proj, bm, bn)
    const int flat = (int)(blockIdx.y * gridDim.x + blockIdx.x);  // 0..1535
    const int k8   = flat & 7;          // XCD id (round-robin on flat)
    const int m    = flat >> 3;         // 0..191 within XCD
    const int proj = m >> 6;            // 0..2   (proj-outer: resident set = 1 proj chunk)
    const int mm   = m & 63;            // 0..63
    const int bm   = (k8 * 8 + (mm >> 3)) * 128;   // XCD k owns bm-rows [8k,8k+8)
    const int bn   = (mm & 7) * 128;

    const unsigned short* W      = proj == 0 ? Wq : (proj == 1 ? Wk : Wv);
    const unsigned short* bias_p = proj == 0 ? bq : (proj == 1 ? bk : bv);

    const int lrow = lane >> 2;           // 0..15
    const int lcol = (lane & 3) * 8;      // 0,8,16,24

    f32x4 acc[4][4];
    for (int i = 0; i < 4; i++)
        for (int j = 0; j < 4; j++)
            acc[i][j] = f32x4{0.f, 0.f, 0.f, 0.f};

    // stage one 32-wide K slab (A+B) into LDS buffer `buf` (4 loads/wave)
    auto stage = [&](int buf, int ks) {
        const int k0 = ks << 5;
#pragma unroll
        for (int t = 0; t < 2; t++) {
            const int r = w * 32 + t * 16;
            GLD_LDS16(&X[(size_t)(bm + r + lrow) * DM + k0 + lcol], &As[buf][r * 32]);
            GLD_LDS16(&W[(size_t)(bn + r + lrow) * DM + k0 + lcol], &Bs[buf][r * 32]);
        }
    };

    auto compute32 = [&](int cur) {
        bf16x8 af[4], bfr[4];
#pragma unroll
        for (int i = 0; i < 4; i++)
            af[i] = *reinterpret_cast<const bf16x8*>(&As[cur][(wm + i * 16 + l15) * 32 + quad * 8]);
#pragma unroll
        for (int j = 0; j < 4; j++)
            bfr[j] = *reinterpret_cast<const bf16x8*>(&Bs[cur][(wn + j * 16 + l15) * 32 + quad * 8]);
#pragma unroll
        for (int i = 0; i < 4; i++)
#pragma unroll
            for (int j = 0; j < 4; j++)
                acc[i][j] = __builtin_amdgcn_mfma_f32_16x16x32_bf16(af[i], bfr[j], acc[i][j], 0, 0, 0);
    };

    // prologue: 2 slabs in flight
    stage(0, 0);
    stage(1, 1);
    // main loop: stage 2 ahead, wait on the stage from 2 iterations ago
    for (int t = 0; t < 30; ++t) {
        stage((t + 2) & 3, t + 2);
        asm volatile("s_waitcnt vmcnt(8)" ::: "memory");   // stage(t) landed
        __builtin_amdgcn_s_barrier();                      // all waves' stage(t) landed
        compute32(t & 3);
    }
    // tail: t = 30 (only stage(31) may be outstanding)
    asm volatile("s_waitcnt vmcnt(4)" ::: "memory");
    __builtin_amdgcn_s_barrier();
    compute32(30 & 3);
    // tail: t = 31
    asm volatile("s_waitcnt vmcnt(0)" ::: "memory");
    __builtin_amdgcn_s_barrier();
    compute32(31 & 3);

    // epilogue: C layout row = quad*4+r, col = l15
    if (proj < 2) {
        unsigned short* dst = (proj == 0) ? Qb : Kb;
#pragma unroll
        for (int j = 0; j < 4; j++) {
            const int   e    = bn + wn + j * 16 + l15;   // 0..1023
            const int   h    = e >> 6, dd = e & 63;
            const float bias = bf2f(bias_p[e]);
#pragma unroll
            for (int i = 0; i < 4; i++) {
#pragma unroll
                for (int r = 0; r < 4; r++) {
                    const int mrow = bm + wm + i * 16 + quad * 4 + r;
                    const int b = mrow >> 11, s = mrow & 2047;
                    dst[((size_t)(b * NH + h) * Sz + s) * DH + dd] = f2bf(acc[i][j][r] + bias);
                }
            }
        }
    } else {
        // V transposed: 4 consecutive s per lane -> one uint2 (4 bf16) store
#pragma unroll
        for (int j = 0; j < 4; j++) {
            const int   e    = bn + wn + j * 16 + l15;
            const int   h    = e >> 6, dd = e & 63;
            const float bias = bf2f(bias_p[e]);
#pragma unroll
            for (int i = 0; i < 4; i++) {
                const int m0 = bm + wm + i * 16 + quad * 4;     // s-aligned to 4
                const int b  = m0 >> 11, s0 = m0 & 2047;
                const unsigned u0 = __float_as_uint(acc[i][j][0] + bias) + 0x8000u;
                const unsigned u1 = __float_as_uint(acc[i][j][1] + bias) + 0x8000u;
                const unsigned u2 = __float_as_uint(acc[i][j][2] + bias) + 0x8000u;
                const unsigned u3 = __float_as_uint(acc[i][j][3] + bias) + 0x8000u;
                uint2 pk;
                pk.x = __builtin_amdgcn_perm(u1, u0, 0x07060302u);
                pk.y = __builtin_amdgcn_perm(u3, u2, 0x07060302u);
                *reinterpret_cast<uint2*>(
                    &Vtb[((size_t)(b * NH + h) * DH + dd) * Sz + s0]) = pk;
            }
        }
    }
}

// ---------------------------------------------------------------------------
// Flash attention (causal), fixed-max softmax, S^T orientation.
// 8 waves x 16 q = 128 q per block; two passes over chunk pair (c, 15-c).
// grid: (8, 64) = 512 blocks = 2/CU x 8 waves = 16 waves/CU steady.
// R9: XCD-locality remap — the 8 cA-blocks sharing a head's K/V (512KB) now
// land on ONE XCD (bh%8 == XCD id); per-XCD resident K/V = 8 heads x 512KB
// = 4MB = L2 size, so K/V staging reads are L2-hits after first touch.
// T14 async-STAGE split kept from R7/R8 (reg-prefetch one 64-tile ahead,
// raw s_barrier after LDS write so the prefetch stays in flight).
// ---------------------------------------------------------------------------
__global__ __launch_bounds__(512) void flash_attn(
    const unsigned short* __restrict__ Qb,    // [64][2048][64]
    const unsigned short* __restrict__ Kb,    // [64][2048][64]
    const unsigned short* __restrict__ Vtb,   // [64][64][2048]
    unsigned short* __restrict__ AOb)         // [4][2048][1024]
{
    __shared__ __align__(16) unsigned short Ks[64 * 72];    // [kv][d]
    __shared__ __align__(16) unsigned short Vs[64 * 72];    // [d][kv]
    __shared__ __align__(16) unsigned short Ps[128 * 72];   // [q][kv], wave-private rows

    const int tid  = threadIdx.x;
    const int w    = tid >> 6, lane = tid & 63;
    const int quad = lane >> 4, l15 = lane & 15;

    // XCD-locality remap: flat -> (bh, cA); bh % 8 == XCD id
    const int flat = (int)(blockIdx.y * gridDim.x + blockIdx.x);  // 0..511
    const int k8   = flat & 7;
    const int m    = flat >> 3;          // 0..63
    const int bh   = k8 + 8 * (m >> 3);  // 8 heads per XCD
    const int cA   = m & 7;

    const int srow = tid >> 3;            // 0..63  (512 threads)
    const int scc  = (tid & 7) * 8;       // 0..56
    const int hh = bh & 15, bb = bh >> 4;

    for (int pass = 0; pass < 2; pass++) {
        const int chunk = pass ? (15 - cA) : cA;
        const int qb = chunk * 128;
        const int qw = qb + w * 16;                  // wave's 16 q rows

        // Q fragment: B-operand layout (row=q=l15, k=quad*8+j)
        const size_t qbase = ((size_t)bh * Sz + qw + l15) * DH;
        const bf16x8 qf0 = *reinterpret_cast<const bf16x8*>(&Qb[qbase + quad * 8]);
        const bf16x8 qf1 = *reinterpret_cast<const bf16x8*>(&Qb[qbase + 32 + quad * 8]);

        f32x4 o[4];
#pragma unroll
        for (int jd = 0; jd < 4; jd++) o[jd] = f32x4{0.f, 0.f, 0.f, 0.f};
        float lsum = 0.f;

        const int n_kv = qb + 128;                   // multiple of 128

        auto compute = [&](int kb) {
            const bool need_mask = (kb + 64 > qw);
#pragma unroll
            for (int j = 0; j < 4; j++) {
                const bf16x8 kf0 = *reinterpret_cast<const bf16x8*>(&Ks[(j * 16 + l15) * 72 + quad * 8]);
                const bf16x8 kf1 = *reinterpret_cast<const bf16x8*>(&Ks[(j * 16 + l15) * 72 + 32 + quad * 8]);
                f32x4 st = f32x4{0.f, 0.f, 0.f, 0.f};
                st = __builtin_amdgcn_mfma_f32_16x16x32_bf16(kf0, qf0, st, 0, 0, 0);
                st = __builtin_amdgcn_mfma_f32_16x16x32_bf16(kf1, qf1, st, 0, 0, 0);
                // p = exp(S/8) = exp2(S * 0.125*log2(e)); causal mask via select
                const int qa = qw + l15;
                float p[4];
#pragma unroll
                for (int r = 0; r < 4; r++) {
                    float e = __builtin_amdgcn_exp2f(st[r] * 0.18033688011f);
                    if (need_mask) {
                        const int kv = kb + j * 16 + quad * 4 + r;
                        e = (kv <= qa) ? e : 0.f;
                    }
                    p[r] = e;
                }
                lsum += (p[0] + p[1]) + (p[2] + p[3]);
                const unsigned u0 = __float_as_uint(p[0]) + 0x8000u;
                const unsigned u1 = __float_as_uint(p[1]) + 0x8000u;
                const unsigned u2 = __float_as_uint(p[2]) + 0x8000u;
                const unsigned u3 = __float_as_uint(p[3]) + 0x8000u;
                const unsigned pk0 = __builtin_amdgcn_perm(u1, u0, 0x07060302u);
                const unsigned pk1 = __builtin_amdgcn_perm(u3, u2, 0x07060302u);
                const int prow = (w * 16 + l15) * 72 + j * 16 + quad * 4;
                *reinterpret_cast<unsigned*>(&Ps[prow])     = pk0;
                *reinterpret_cast<unsigned*>(&Ps[prow + 2]) = pk1;
            }

            // wave-private Ps rows: in-wave drain only, no barrier
            asm volatile("s_waitcnt lgkmcnt(0)" ::: "memory");

            const bf16x8 pf0 = *reinterpret_cast<const bf16x8*>(&Ps[(w * 16 + l15) * 72 + quad * 8]);
            const bf16x8 pf1 = *reinterpret_cast<const bf16x8*>(&Ps[(w * 16 + l15) * 72 + 32 + quad * 8]);
#pragma unroll
            for (int jd = 0; jd < 4; jd++) {
                const bf16x8 vf0 = *reinterpret_cast<const bf16x8*>(&Vs[(jd * 16 + l15) * 72 + quad * 8]);
                const bf16x8 vf1 = *reinterpret_cast<const bf16x8*>(&Vs[(jd * 16 + l15) * 72 + 32 + quad * 8]);
                o[jd] = __builtin_amdgcn_mfma_f32_16x16x32_bf16(pf0, vf0, o[jd], 0, 0, 0);
                o[jd] = __builtin_amdgcn_mfma_f32_16x16x32_bf16(pf1, vf1, o[jd], 0, 0, 0);
            }
        };

        // prologue: prefetch tile 0 into registers
        uint4 kr0 = *reinterpret_cast<const uint4*>(&Kb[((size_t)bh * Sz + srow) * DH + scc]);
        uint4 vr0 = *reinterpret_cast<const uint4*>(&Vtb[((size_t)bh * DH + srow) * Sz + scc]);
        uint4 kr1, vr1;

        for (int kb = 0; kb < n_kv; kb += 128) {
            // ---------------- tile kb (regs kr0/vr0) ----------------
            __syncthreads();    // prev compute done; drains kr0/vr0 (used now)
            *reinterpret_cast<uint4*>(&Ks[srow * 72 + scc]) = kr0;
            *reinterpret_cast<uint4*>(&Vs[srow * 72 + scc]) = vr0;
            // prefetch tile kb+64 (always exists: n_kv is a multiple of 128)
            kr1 = *reinterpret_cast<const uint4*>(&Kb[((size_t)bh * Sz + kb + 64 + srow) * DH + scc]);
            vr1 = *reinterpret_cast<const uint4*>(&Vtb[((size_t)bh * DH + srow) * Sz + kb + 64 + scc]);
            asm volatile("s_waitcnt lgkmcnt(0)" ::: "memory");
            __builtin_amdgcn_s_barrier();             // raw: keep prefetch in flight
            asm volatile("" ::: "memory");
            if (kb <= qw + 15) compute(kb);

            // ---------------- tile kb+64 (regs kr1/vr1) ----------------
            __syncthreads();
            *reinterpret_cast<uint4*>(&Ks[srow * 72 + scc]) = kr1;
            *reinterpret_cast<uint4*>(&Vs[srow * 72 + scc]) = vr1;
            if (kb + 128 < n_kv) {
                kr0 = *reinterpret_cast<const uint4*>(&Kb[((size_t)bh * Sz + kb + 128 + srow) * DH + scc]);
                vr0 = *reinterpret_cast<const uint4*>(&Vtb[((size_t)bh * DH + srow) * Sz + kb + 128 + scc]);
            }
            asm volatile("s_waitcnt lgkmcnt(0)" ::: "memory");
            __builtin_amdgcn_s_barrier();
            asm volatile("" ::: "memory");
            if (kb + 64 <= qw + 15) compute(kb + 64);
        }

        // reduce lsum across quads (lane holds partial for q = qw + l15)
        lsum += __shfl_xor(lsum, 16);
        lsum += __shfl_xor(lsum, 32);

        // write AO[b][s][h*64+d]; o[jd][r] is q-row quad*4+r, col jd*16+l15
        float linv[4];
#pragma unroll
        for (int r = 0; r < 4; r++)
            linv[r] = 1.0f / __shfl(lsum, quad * 4 + r);
#pragma unroll
        for (int jd = 0; jd < 4; jd++) {
#pragma unroll
            for (int r = 0; r < 4; r++) {
                const int s = qw + quad * 4 + r;
                AOb[((size_t)(bb * Sz + s)) * DM + hh * DH + jd * 16 + l15] =
                    f2bf(o[jd][r] * linv[r]);
            }
        }
    }
}

// ---------------------------------------------------------------------------
// Output projection: out = AO[8192,1024] @ Wo[1024,1024]^T + bo
// Stores f32 or bf16 per the dtype flag.  grid: (8, 64) = 512 blocks.
// R9: XCD-locality remap — XCD k owns bm-rows [8k,8k+8) x all 8 bn.
// Resident per XCD: A-chunk 2MB + Wo 2MB = 4MB = L2. All 64 blocks of an
// XCD are simultaneously resident (512 blocks = 2/CU), so the whole set
// runs against a warm L2. Depth-2/nbuf-4 pipeline kept.
// ---------------------------------------------------------------------------
__global__ __launch_bounds__(256) void gemm_out(
    const unsigned short* __restrict__ A,
    const unsigned short* __restrict__ W,
    const unsigned short* __restrict__ bo,
    void* __restrict__ outv,
    const int* __restrict__ flagp)
{
    __shared__ __align__(16) unsigned short As[4][128 * 32];
    __shared__ __align__(16) unsigned short Bs[4][128 * 32];
    const int tid  = threadIdx.x;
    const int w    = tid >> 6, lane = tid & 63;
    const int quad = lane >> 4, l15 = lane & 15;
    const int wm   = (w & 1) * 64, wn = (w >> 1) * 64;

    // XCD-locality remap: flat -> (bm, bn)
    const int flat = (int)(blockIdx.y * gridDim.x + blockIdx.x);  // 0..511
    const int k8   = flat & 7;
    const int m    = flat >> 3;          // 0..63
    const int bm   = (k8 * 8 + (m >> 3)) * 128;
    const int bn   = (m & 7) * 128;

    const int lrow = lane >> 2;
    const int lcol = (lane & 3) * 8;

    f32x4 acc[4][4];
    for (int i = 0; i < 4; i++)
        for (int j = 0; j < 4; j++)
            acc[i][j] = f32x4{0.f, 0.f, 0.f, 0.f};

    auto stage = [&](int buf, int ks) {
        const int k0 = ks << 5;
#pragma unroll
        for (int t = 0; t < 2; t++) {
            const int r = w * 32 + t * 16;
            GLD_LDS16(&A[(size_t)(bm + r + lrow) * DM + k0 + lcol], &As[buf][r * 32]);
            GLD_LDS16(&W[(size_t)(bn + r + lrow) * DM + k0 + lcol], &Bs[buf][r * 32]);
        }
    };

    auto compute32 = [&](int cur) {
        bf16x8 af[4], bfr[4];
#pragma unroll
        for (int i = 0; i < 4; i++)
            af[i] = *reinterpret_cast<const bf16x8*>(&As[cur][(wm + i * 16 + l15) * 32 + quad * 8]);
#pragma unroll
        for (int j = 0; j < 4; j++)
            bfr[j] = *reinterpret_cast<const bf16x8*>(&Bs[cur][(wn + j * 16 + l15) * 32 + quad * 8]);
#pragma unroll
        for (int i = 0; i < 4; i++)
#pragma unroll
            for (int j = 0; j < 4; j++)
                acc[i][j] = __builtin_amdgcn_mfma_f32_16x16x32_bf16(af[i], bfr[j], acc[i][j], 0, 0, 0);
    };

    stage(0, 0);
    stage(1, 1);
    for (int t = 0; t < 30; ++t) {
        stage((t + 2) & 3, t + 2);
        asm volatile("s_waitcnt vmcnt(8)" ::: "memory");
        __builtin_amdgcn_s_barrier();
        compute32(t & 3);
    }
    asm volatile("s_waitcnt vmcnt(4)" ::: "memory");
    __builtin_amdgcn_s_barrier();
    compute32(30 & 3);
    asm volatile("s_waitcnt vmcnt(0)" ::: "memory");
    __builtin_amdgcn_s_barrier();
    compute32(31 & 3);

    const int flag = *flagp;
    float*          outf = (float*)outv;
    unsigned short* outh = (unsigned short*)outv;
#pragma unroll
    for (int j = 0; j < 4; j++) {
        const int   e    = bn + wn + j * 16 + l15;
        const float bias = bf2f(bo[e]);
#pragma unroll
        for (int i = 0; i < 4; i++) {
#pragma unroll
            for (int r = 0; r < 4; r++) {
                const int   mrow = bm + wm + i * 16 + quad * 4 + r;
                const float v = acc[i][j][r] + bias;
                if (flag) outf[(size_t)mrow * DM + e] = v;
                else      outh[(size_t)mrow * DM + e] = f2bf(v);
            }
        }
    }
}

// ---------------------------------------------------------------------------
extern "C" void kernel_launch(void* const* d_in, const int* in_sizes, int n_in,
                              void* d_out, int out_size, void* d_ws, size_t ws_size,
                              hipStream_t stream) {
    // Bind inputs by ELEMENT COUNT (dtype/mask-presence robust)
    const void* x = nullptr;
    const void* Wsrc[4] = {nullptr, nullptr, nullptr, nullptr};
    const void* bsrc[4] = {nullptr, nullptr, nullptr, nullptr};
    int nw = 0, nb = 0;
    for (int i = 0; i < n_in; i++) {
        const int sz = in_sizes[i];
        if (sz == Bz * Sz * DM)            { if (!x) x = d_in[i]; }
        else if (sz == DM * DM)            { if (nw < 4) Wsrc[nw++] = d_in[i]; }
        else if (sz == DM)                 { if (nb < 4) bsrc[nb++] = d_in[i]; }
    }

    char* wsb = (char*)d_ws;
    int*  flagp = (int*)wsb;
    unsigned short* Xc  = (unsigned short*)(wsb + 16);
    const size_t NX = (size_t)Bz * Sz * DM;       // 8,388,608
    const size_t NW = (size_t)DM * DM;            // 1,048,576
    unsigned short* Wc0 = Xc  + NX;
    unsigned short* Wc1 = Wc0 + NW;
    unsigned short* Wc2 = Wc1 + NW;
    unsigned short* Wc3 = Wc2 + NW;
    unsigned short* bc0 = Wc3 + NW;
    unsigned short* bc1 = bc0 + DM;
    unsigned short* bc2 = bc1 + DM;
    unsigned short* bc3 = bc2 + DM;
    unsigned short* Qb  = bc3 + DM;
    const size_t SZ = (size_t)Bz * NH * Sz * DH;  // 8,388,608
    unsigned short* Kb  = Qb  + SZ;
    unsigned short* Vtb = Kb  + SZ;
    unsigned short* AOb = Vtb + SZ;

    detect_dtype<<<1, 64, 0, stream>>>((const unsigned short*)x, flagp);
    convert_inputs<<<dim3(512, 9), 256, 0, stream>>>(
        x, Wsrc[0], Wsrc[1], Wsrc[2], Wsrc[3],
        bsrc[0], bsrc[1], bsrc[2], bsrc[3],
        Xc, Wc0, Wc1, Wc2, Wc3, bc0, bc1, bc2, bc3, flagp);

    gemm_qkv <<<dim3(24, 64), 256, 0, stream>>>(Xc, Wc0, Wc1, Wc2, bc0, bc1, bc2, Qb, Kb, Vtb);
    flash_attn<<<dim3(8, 64), 512, 0, stream>>>(Qb, Kb, Vtb, AOb);
    gemm_out <<<dim3(8, 64), 256, 0, stream>>>(AOb, Wc3, bc3, d_out, flagp);
}